// Round 2
// 4802.273 us; speedup vs baseline: 1.6519x; 1.6519x over previous
//
#include <hip/hip_runtime.h>
#include <hip/hip_cooperative_groups.h>

#define BB 64      // batch
#define TT 256     // time
#define EE 256     // embed dim
#define NU 1024    // hidden units
#define N3 3072    // 3*NU

// ---------------------------------------------------------------------------
// Kernel 0a: pack U[k][g*NU+u] -> Upack[u*3+g][k]
// ---------------------------------------------------------------------------
__global__ __launch_bounds__(256) void upack_kernel(
    const float* __restrict__ U, float* __restrict__ up)
{
    __shared__ float t32[32][33];
    const int c0 = blockIdx.x * 32, k0 = blockIdx.y * 32;
    const int tx = threadIdx.x & 31, ty = threadIdx.x >> 5;
    #pragma unroll
    for (int i = 0; i < 4; ++i) {
        int k = ty + i * 8;
        t32[k][tx] = U[(size_t)(k0 + k) * N3 + c0 + tx];
    }
    __syncthreads();
    #pragma unroll
    for (int i = 0; i < 4; ++i) {
        int cl = ty + i * 8;
        int c = c0 + cl;
        int u = c & 1023, g = c >> 10;
        up[(size_t)(u * 3 + g) * NU + k0 + tx] = t32[tx][cl];
    }
}

// ---------------------------------------------------------------------------
// Kernel 0b: transpose tokens; 0c: init hT (k-major) + zero barrier counters
// ---------------------------------------------------------------------------
__global__ __launch_bounds__(64) void tokT_kernel(
    const int* __restrict__ x, int* __restrict__ xT)
{
    const int t = blockIdx.x, b = threadIdx.x;
    xT[t * BB + b] = x[b * TT + t];
}

__global__ __launch_bounds__(256) void hinit_kernel(
    const float* __restrict__ hidden, float* __restrict__ hT, unsigned* __restrict__ cnt)
{
    const int u = blockIdx.x * 4 + (threadIdx.x >> 6);
    const int b = threadIdx.x & 63;
    hT[u * BB + b] = hidden[(size_t)b * NU + u];
    if (blockIdx.x == 0 && threadIdx.x < TT) cnt[threadIdx.x] = 0u;
}

// ---------------------------------------------------------------------------
// Kernel 1: xprojT[t][c][b] = (emb[x[b,t]] @ W + b0)[c]
// ---------------------------------------------------------------------------
__global__ __launch_bounds__(256) void xprojT_kernel(
    const int* __restrict__ x, const float* __restrict__ emb,
    const float* __restrict__ W, const float* __restrict__ bias,
    float* __restrict__ xpT)
{
    __shared__ float AsT[32][132];
    __shared__ float Ws[32][132];
    __shared__ int toks[128];

    const int tid = threadIdx.x;
    const int mt = blockIdx.x / 24, nt = blockIdx.x % 24;
    const int m0 = mt * 128, n0 = nt * 128;

    if (tid < 128) {
        int mg = m0 + tid;
        toks[tid] = x[(mg & 63) * TT + (mg >> 6)];
    }
    __syncthreads();

    const int tx = tid & 15, ty = tid >> 4;
    float acc[8][8] = {};

    for (int kb = 0; kb < 8; ++kb) {
        const int k0 = kb * 32;
        if (kb) __syncthreads();
        #pragma unroll
        for (int i = 0; i < 4; ++i) {
            int idx = tid + 256 * i;
            int m = idx >> 3, c4 = idx & 7;
            float4 av = *(const float4*)(emb + (size_t)toks[m] * EE + k0 + c4 * 4);
            AsT[c4 * 4 + 0][m] = av.x; AsT[c4 * 4 + 1][m] = av.y;
            AsT[c4 * 4 + 2][m] = av.z; AsT[c4 * 4 + 3][m] = av.w;
            int r = idx >> 5, w4 = idx & 31;
            *(float4*)&Ws[r][w4 * 4] =
                *(const float4*)(W + (size_t)(k0 + r) * N3 + n0 + w4 * 4);
        }
        __syncthreads();
        #pragma unroll 8
        for (int kk = 0; kk < 32; ++kk) {
            float a8[8], w8[8];
            *(float4*)a8       = *(const float4*)&AsT[kk][ty * 8];
            *(float4*)(a8 + 4) = *(const float4*)&AsT[kk][ty * 8 + 4];
            *(float4*)w8       = *(const float4*)&Ws[kk][tx * 8];
            *(float4*)(w8 + 4) = *(const float4*)&Ws[kk][tx * 8 + 4];
            #pragma unroll
            for (int i = 0; i < 8; ++i)
                #pragma unroll
                for (int j = 0; j < 8; ++j) acc[i][j] += a8[i] * w8[j];
        }
    }

    float b8[8];
    *(float4*)b8       = *(const float4*)(bias + n0 + tx * 8);
    *(float4*)(b8 + 4) = *(const float4*)(bias + n0 + tx * 8 + 4);
    const int t0 = mt * 2 + (ty >> 3);
    const int bb0 = (ty & 7) * 8;
    #pragma unroll
    for (int j = 0; j < 8; ++j) {
        const int c = n0 + tx * 8 + j;
        float4 lo, hi;
        lo.x = acc[0][j] + b8[j]; lo.y = acc[1][j] + b8[j];
        lo.z = acc[2][j] + b8[j]; lo.w = acc[3][j] + b8[j];
        hi.x = acc[4][j] + b8[j]; hi.y = acc[5][j] + b8[j];
        hi.z = acc[6][j] + b8[j]; hi.w = acc[7][j] + b8[j];
        size_t base = ((size_t)t0 * N3 + c) * BB + bb0;
        *(float4*)(xpT + base)     = lo;
        *(float4*)(xpT + base + 4) = hi;
    }
}

// ---------------------------------------------------------------------------
// Kernel 2: persistent GRU scan, 256 blocks x 512 threads (coop launch).
// Coherence protocol unchanged (proven in prior session):
//   - h / per-step outputs: __hip_atomic_store RELAXED/SYSTEM write-through
//     (no dirty L2 lines anywhere; LLC always fresh)
//   - h / xpT loads: plain cached loads
//   - per step: drain stores, counter barrier, acquire fence -> buffer_inv
//
// GEMM structure (this round: LDS-based kk-reduction, no permlane):
//   - lane = (bq = lane&15 -> 4 contiguous batches, kk = lane>>4 -> k-chunk)
//     each 16B U broadcast read feeds 16 FMAs: DS reads 384->96/wave
//   - U in LDS as [w][s][c][kk]: the wave's 4 distinct read addresses are
//     16 consecutive banks -> conflict-free broadcast
//   - h loaded as float4 (32 loads/thread), software prefetch 3 deep
//   - per-thread float4 partials written to red4[w][kk][s][bq]
//     (12 ds_write_b128); gating threads sum 32 partials per gate with
//     linear conflict-free ds_read_b32 -- no cross-lane instructions
//   - per-step output written into the consumed xz slice of xpT (coalesced,
//     same thread read-then-write); final [T][U][B] -> [B][T][U] transpose
//     kernel replaces the 64-way-scattered out stores.
// ---------------------------------------------------------------------------
__global__ __launch_bounds__(512) void gru_persist(
    const int* __restrict__ xT, const float* __restrict__ upack,
    const float* __restrict__ bias, float* xpT,
    float* __restrict__ out, const float* __restrict__ hidden,
    float* hf0, float* hf1, unsigned* cnt)
{
    __shared__ float4 Us4[8][12][8][4];    // 48 KB: [w][s][c][kk]
    __shared__ float4 red4[8][4][12][16];  // 96 KB: [w][kk][s][bq] partials

    const int tid = threadIdx.x;
    const int u0 = blockIdx.x * 4;
    const int w = tid >> 6;                // wave: k-eighth; unit j for tid<256
    const int lane = tid & 63;
    const int bq = lane & 15;              // batch quad -> batches 4bq..4bq+3
    const int kk = lane >> 4;              // k sub-chunk within wave

    // preload U slice into LDS, laid out for conflict-free broadcast reads
    for (int i = tid; i < 12 * 256; i += 512) {
        int s = i >> 8, k4 = i & 255;      // k = 4*k4
        int ww = k4 >> 5, kx = (k4 >> 3) & 3, c = k4 & 7;
        Us4[ww][s][c][kx] = *(const float4*)(upack + (size_t)(u0 * 3 + s) * NU + k4 * 4);
    }

    float hold = 0.f, brz = 0.f, brr = 0.f, brh = 0.f;
    if (tid < 256) {
        hold = hidden[(size_t)lane * NU + u0 + w];
        brz = bias[N3 + 0 * NU + u0 + w];
        brr = bias[N3 + 1 * NU + u0 + w];
        brh = bias[N3 + 2 * NU + u0 + w];
    }
    float* state_out = out + (size_t)BB * TT * NU;
    __syncthreads();

    const float* hc = hf0;
    float* hn = hf1;

    for (int t = 0; t < TT; ++t) {
        // ---- prefetch gating inputs (L2 cold after buffer_inv); they
        //      resolve under the GEMM and are consumed after the barrier
        float xz = 0.f, xr = 0.f, xh = 0.f; int tok = 1;
        if (tid < 256) {
            size_t xb = ((size_t)t * N3 + u0 + w) * BB + lane;
            xz = xpT[xb];
            xr = xpT[xb + (size_t)NU * BB];
            xh = xpT[xb + (size_t)2 * NU * BB];
            tok = xT[t * BB + lane];
        }

        // ---- recurrent GEMM over this thread's 32-k chunk x 4 batches ----
        float4 acc[12] = {};
        const float* hp = hc + (size_t)(w * 128 + kk * 32) * BB + 4 * bq;
        const float4* Up = (const float4*)&Us4[w][0][0][kk];
        float4 hb[8][4];

        #define LOADH(c_) do {                                               \
            hb[c_][0] = *(const float4*)(hp + ((c_) * 4 + 0) * BB);          \
            hb[c_][1] = *(const float4*)(hp + ((c_) * 4 + 1) * BB);          \
            hb[c_][2] = *(const float4*)(hp + ((c_) * 4 + 2) * BB);          \
            hb[c_][3] = *(const float4*)(hp + ((c_) * 4 + 3) * BB);          \
        } while (0)

        LOADH(0); LOADH(1); LOADH(2);
        #pragma unroll
        for (int c = 0; c < 8; ++c) {
            if (c < 5) LOADH(c + 3);       // prefetch distance 3 iterations
            #pragma unroll
            for (int s = 0; s < 12; ++s) {
                float4 u = Up[(s * 8 + c) * 4];
                acc[s].x += u.x * hb[c][0].x + u.y * hb[c][1].x + u.z * hb[c][2].x + u.w * hb[c][3].x;
                acc[s].y += u.x * hb[c][0].y + u.y * hb[c][1].y + u.z * hb[c][2].y + u.w * hb[c][3].y;
                acc[s].z += u.x * hb[c][0].z + u.y * hb[c][1].z + u.z * hb[c][2].z + u.w * hb[c][3].z;
                acc[s].w += u.x * hb[c][0].w + u.y * hb[c][1].w + u.z * hb[c][2].w + u.w * hb[c][3].w;
            }
        }
        #undef LOADH

        // ---- write per-thread partials (batches contiguous: b128) ----
        #pragma unroll
        for (int s = 0; s < 12; ++s) red4[w][kk][s][bq] = acc[s];
        __syncthreads();

        // ---- gating (tid < 256): unit u0+w, batch lane ----
        if (tid < 256) {
            const int j = w;
            const int bqi = lane >> 2, bc = lane & 3;
            float rz = brz, rr = brr, rh = brh;
            #pragma unroll
            for (int q = 0; q < 8; ++q)
                #pragma unroll
                for (int kx = 0; kx < 4; ++kx) {
                    rz += ((const float*)&red4[q][kx][j * 3 + 0][bqi])[bc];
                    rr += ((const float*)&red4[q][kx][j * 3 + 1][bqi])[bc];
                    rh += ((const float*)&red4[q][kx][j * 3 + 2][bqi])[bc];
                }
            float z  = 1.f / (1.f + expf(-(xz + rz)));
            float r  = 1.f / (1.f + expf(-(xr + rr)));
            float hh = tanhf(xh + r * rh);
            float hnew = z * hold + (1.f - z) * hh;
            if (tok == 0) hnew = hold;     // mask_zero: carry state

            // write-through stores (LLC-visible, no dirty L2 lines)
            __hip_atomic_store(&hn[(u0 + j) * BB + lane], hnew,
                               __ATOMIC_RELAXED, __HIP_MEMORY_SCOPE_SYSTEM);
            // per-step output -> consumed xz slice of xpT (coalesced);
            // transposed to out[] by outT_kernel afterwards
            __hip_atomic_store(&xpT[((size_t)t * N3 + u0 + j) * BB + lane], hnew,
                               __ATOMIC_RELAXED, __HIP_MEMORY_SCOPE_SYSTEM);
            if (t == TT - 1)
                __hip_atomic_store(&state_out[(size_t)lane * NU + u0 + j], hnew,
                                   __ATOMIC_RELAXED, __HIP_MEMORY_SCOPE_SYSTEM);
            hold = hnew;
        }

        // ---- barrier: drain WT stores, arrive, spin, acquire-inv ----
        __builtin_amdgcn_s_waitcnt(0);
        __syncthreads();
        if (tid == 0) {
            __hip_atomic_fetch_add(&cnt[t], 1u,
                                   __ATOMIC_RELAXED, __HIP_MEMORY_SCOPE_SYSTEM);
            unsigned v;
            long guard = 0;
            do {
                v = __hip_atomic_load(&cnt[t],
                                      __ATOMIC_RELAXED, __HIP_MEMORY_SCOPE_SYSTEM);
                if (v < 256u) __builtin_amdgcn_s_sleep(1);
            } while (v < 256u && ++guard < (1L << 24));
            // invalidate L1+L2 so next step's plain loads re-fetch from LLC
            __builtin_amdgcn_fence(__ATOMIC_ACQUIRE, "");
        }
        __syncthreads();

        float* tmp = (float*)hc; hc = hn; hn = tmp;
    }
}

// ---------------------------------------------------------------------------
// Kernel 3: transpose per-step outputs from xpT's xz slices [T][U][B]
// into out [B][T][U]. Kernel-boundary cache semantics make the persist
// kernel's write-through stores visible.
// ---------------------------------------------------------------------------
__global__ __launch_bounds__(256) void outT_kernel(
    const float* __restrict__ xpT, float* __restrict__ out)
{
    __shared__ float tile[64][65];
    const int t = blockIdx.x, u0 = blockIdx.y * 64;
    const int lane = threadIdx.x & 63, row = threadIdx.x >> 6;
    #pragma unroll
    for (int r = row; r < 64; r += 4)
        tile[r][lane] = xpT[((size_t)t * N3 + u0 + r) * BB + lane];
    __syncthreads();
    #pragma unroll
    for (int b = row; b < 64; b += 4)
        out[((size_t)b * TT + t) * NU + u0 + lane] = tile[lane][b];
}

// ---------------------------------------------------------------------------
extern "C" void kernel_launch(void* const* d_in, const int* in_sizes, int n_in,
                              void* d_out, int out_size, void* d_ws, size_t ws_size,
                              hipStream_t stream) {
    const int*   x      = (const int*)d_in[0];
    const float* hidden = (const float*)d_in[1];
    const float* emb    = (const float*)d_in[2];
    const float* W      = (const float*)d_in[3];
    const float* U      = (const float*)d_in[4];
    const float* bvec   = (const float*)d_in[5];

    float* out = (float*)d_out;

    float*    xpT   = (float*)d_ws;                       // 50,331,648 floats
    float*    upack = xpT + (size_t)16384 * N3;           //  3,145,728 floats
    float*    h0    = upack + (size_t)3 * NU * NU;        //     65,536 floats
    float*    h1    = h0 + (size_t)NU * BB;               //     65,536 floats
    int*      xT    = (int*)(h1 + (size_t)NU * BB);       //     16,384 ints
    unsigned* cnt   = (unsigned*)(xT + TT * BB);          //        256 uints

    upack_kernel<<<dim3(96, 32), dim3(256), 0, stream>>>(U, upack);
    tokT_kernel<<<dim3(TT), dim3(64), 0, stream>>>(x, xT);
    hinit_kernel<<<dim3(256), dim3(256), 0, stream>>>(hidden, h0, cnt);
    xprojT_kernel<<<dim3(3072), dim3(256), 0, stream>>>(x, emb, W, bvec, xpT);

    void* args[] = {(void*)&xT, (void*)&upack, (void*)&bvec, (void*)&xpT,
                    (void*)&out, (void*)&hidden, (void*)&h0, (void*)&h1,
                    (void*)&cnt};
    hipLaunchCooperativeKernel((const void*)gru_persist, dim3(256), dim3(512),
                               args, 0, stream);

    outT_kernel<<<dim3(TT, 16), dim3(256), 0, stream>>>(xpT, out);
}

// Round 3
// 3854.856 us; speedup vs baseline: 2.0579x; 1.2458x over previous
//
#include <hip/hip_runtime.h>
#include <hip/hip_cooperative_groups.h>

#define BB 64      // batch
#define TT 256     // time
#define EE 256     // embed dim
#define NU 1024    // hidden units
#define N3 3072    // 3*NU

// ---------------------------------------------------------------------------
// Kernel 0a: pack U[k][g*NU+u] -> Upack[u*3+g][k]
// ---------------------------------------------------------------------------
__global__ __launch_bounds__(256) void upack_kernel(
    const float* __restrict__ U, float* __restrict__ up)
{
    __shared__ float t32[32][33];
    const int c0 = blockIdx.x * 32, k0 = blockIdx.y * 32;
    const int tx = threadIdx.x & 31, ty = threadIdx.x >> 5;
    #pragma unroll
    for (int i = 0; i < 4; ++i) {
        int k = ty + i * 8;
        t32[k][tx] = U[(size_t)(k0 + k) * N3 + c0 + tx];
    }
    __syncthreads();
    #pragma unroll
    for (int i = 0; i < 4; ++i) {
        int cl = ty + i * 8;
        int c = c0 + cl;
        int u = c & 1023, g = c >> 10;
        up[(size_t)(u * 3 + g) * NU + k0 + tx] = t32[tx][cl];
    }
}

// ---------------------------------------------------------------------------
// Kernel 0b: transpose tokens; 0c: init hT (k-major) + zero barrier counters
// ---------------------------------------------------------------------------
__global__ __launch_bounds__(64) void tokT_kernel(
    const int* __restrict__ x, int* __restrict__ xT)
{
    const int t = blockIdx.x, b = threadIdx.x;
    xT[t * BB + b] = x[b * TT + t];
}

__global__ __launch_bounds__(256) void hinit_kernel(
    const float* __restrict__ hidden, float* __restrict__ hT, unsigned* __restrict__ cnt)
{
    const int u = blockIdx.x * 4 + (threadIdx.x >> 6);
    const int b = threadIdx.x & 63;
    hT[u * BB + b] = hidden[(size_t)b * NU + u];
    if (blockIdx.x == 0 && threadIdx.x < 256) {
        cnt[threadIdx.x] = 0u;           // group counters (8 x 32-uint pad)
        cnt[threadIdx.x + 256] = 0u;     // root counter at cnt[256]
    }
}

// ---------------------------------------------------------------------------
// Kernel 1: xprojT[t][c][b] = (emb[x[b,t]] @ W + b0)[c]
// ---------------------------------------------------------------------------
__global__ __launch_bounds__(256) void xprojT_kernel(
    const int* __restrict__ x, const float* __restrict__ emb,
    const float* __restrict__ W, const float* __restrict__ bias,
    float* __restrict__ xpT)
{
    __shared__ float AsT[32][132];
    __shared__ float Ws[32][132];
    __shared__ int toks[128];

    const int tid = threadIdx.x;
    const int mt = blockIdx.x / 24, nt = blockIdx.x % 24;
    const int m0 = mt * 128, n0 = nt * 128;

    if (tid < 128) {
        int mg = m0 + tid;
        toks[tid] = x[(mg & 63) * TT + (mg >> 6)];
    }
    __syncthreads();

    const int tx = tid & 15, ty = tid >> 4;
    float acc[8][8] = {};

    for (int kb = 0; kb < 8; ++kb) {
        const int k0 = kb * 32;
        if (kb) __syncthreads();
        #pragma unroll
        for (int i = 0; i < 4; ++i) {
            int idx = tid + 256 * i;
            int m = idx >> 3, c4 = idx & 7;
            float4 av = *(const float4*)(emb + (size_t)toks[m] * EE + k0 + c4 * 4);
            AsT[c4 * 4 + 0][m] = av.x; AsT[c4 * 4 + 1][m] = av.y;
            AsT[c4 * 4 + 2][m] = av.z; AsT[c4 * 4 + 3][m] = av.w;
            int r = idx >> 5, w4 = idx & 31;
            *(float4*)&Ws[r][w4 * 4] =
                *(const float4*)(W + (size_t)(k0 + r) * N3 + n0 + w4 * 4);
        }
        __syncthreads();
        #pragma unroll 8
        for (int kk = 0; kk < 32; ++kk) {
            float a8[8], w8[8];
            *(float4*)a8       = *(const float4*)&AsT[kk][ty * 8];
            *(float4*)(a8 + 4) = *(const float4*)&AsT[kk][ty * 8 + 4];
            *(float4*)w8       = *(const float4*)&Ws[kk][tx * 8];
            *(float4*)(w8 + 4) = *(const float4*)&Ws[kk][tx * 8 + 4];
            #pragma unroll
            for (int i = 0; i < 8; ++i)
                #pragma unroll
                for (int j = 0; j < 8; ++j) acc[i][j] += a8[i] * w8[j];
        }
    }

    float b8[8];
    *(float4*)b8       = *(const float4*)(bias + n0 + tx * 8);
    *(float4*)(b8 + 4) = *(const float4*)(bias + n0 + tx * 8 + 4);
    const int t0 = mt * 2 + (ty >> 3);
    const int bb0 = (ty & 7) * 8;
    #pragma unroll
    for (int j = 0; j < 8; ++j) {
        const int c = n0 + tx * 8 + j;
        float4 lo, hi;
        lo.x = acc[0][j] + b8[j]; lo.y = acc[1][j] + b8[j];
        lo.z = acc[2][j] + b8[j]; lo.w = acc[3][j] + b8[j];
        hi.x = acc[4][j] + b8[j]; hi.y = acc[5][j] + b8[j];
        hi.z = acc[6][j] + b8[j]; hi.w = acc[7][j] + b8[j];
        size_t base = ((size_t)t0 * N3 + c) * BB + bb0;
        *(float4*)(xpT + base)     = lo;
        *(float4*)(xpT + base + 4) = hi;
    }
}

// ---------------------------------------------------------------------------
// Kernel 2: persistent GRU scan, 256 blocks x 512 threads (coop launch).
// Coherence protocol unchanged (proven):
//   - h / per-step outputs: __hip_atomic_store RELAXED/SYSTEM write-through
//   - h / xpT loads: plain cached loads
//   - per step: drain stores, tree barrier, acquire fence -> buffer_inv
//
// This round:
//   - monotonic two-level tree barrier: 8 padded group counters (32
//     contenders each, own 128B line) + 1 root (8 contenders). No resets:
//     group rep is the arrival seeing old == 32t+31; spin on root >= 8(t+1).
//     Replaces the 256-way same-line fetch_add serialization.
//   - t+1 gating loads (xz/xr/xh/tok) issued during the barrier spin, after
//     the store drain. Safe: each block's gating slice of xpT is written
//     only by itself at step t+1 (after consuming), xT immutable. Their HBM
//     latency hides under the spin; values survive buffer_inv in registers.
// ---------------------------------------------------------------------------
__global__ __launch_bounds__(512) void gru_persist(
    const int* __restrict__ xT, const float* __restrict__ upack,
    const float* __restrict__ bias, float* xpT,
    float* __restrict__ out, const float* __restrict__ hidden,
    float* hf0, float* hf1, unsigned* cnt)
{
    __shared__ float4 Us4[8][12][8][4];    // 48 KB: [w][s][c][kk]
    __shared__ float4 red4[8][4][12][16];  // 96 KB: [w][kk][s][bq] partials

    const int tid = threadIdx.x;
    const int u0 = blockIdx.x * 4;
    const int w = tid >> 6;                // wave: k-eighth; unit j for tid<256
    const int lane = tid & 63;
    const int bq = lane & 15;              // batch quad -> batches 4bq..4bq+3
    const int kk = lane >> 4;              // k sub-chunk within wave

    // preload U slice into LDS, laid out for conflict-free broadcast reads
    for (int i = tid; i < 12 * 256; i += 512) {
        int s = i >> 8, k4 = i & 255;      // k = 4*k4
        int ww = k4 >> 5, kx = (k4 >> 3) & 3, c = k4 & 7;
        Us4[ww][s][c][kx] = *(const float4*)(upack + (size_t)(u0 * 3 + s) * NU + k4 * 4);
    }

    float hold = 0.f, brz = 0.f, brr = 0.f, brh = 0.f;
    float xz = 0.f, xr = 0.f, xh = 0.f; int tok = 1;
    if (tid < 256) {
        hold = hidden[(size_t)lane * NU + u0 + w];
        brz = bias[N3 + 0 * NU + u0 + w];
        brr = bias[N3 + 1 * NU + u0 + w];
        brh = bias[N3 + 2 * NU + u0 + w];
        // t = 0 gating inputs
        size_t xb = ((size_t)0 * N3 + u0 + w) * BB + lane;
        xz = xpT[xb];
        xr = xpT[xb + (size_t)NU * BB];
        xh = xpT[xb + (size_t)2 * NU * BB];
        tok = xT[0 * BB + lane];
    }
    float* state_out = out + (size_t)BB * TT * NU;
    __syncthreads();

    const float* hc = hf0;
    float* hn = hf1;

    for (int t = 0; t < TT; ++t) {
        // ---- recurrent GEMM over this thread's 32-k chunk x 4 batches ----
        float4 acc[12] = {};
        const float* hp = hc + (size_t)(w * 128 + kk * 32) * BB + 4 * bq;
        const float4* Up = (const float4*)&Us4[w][0][0][kk];
        float4 hb[8][4];

        #define LOADH(c_) do {                                               \
            hb[c_][0] = *(const float4*)(hp + ((c_) * 4 + 0) * BB);          \
            hb[c_][1] = *(const float4*)(hp + ((c_) * 4 + 1) * BB);          \
            hb[c_][2] = *(const float4*)(hp + ((c_) * 4 + 2) * BB);          \
            hb[c_][3] = *(const float4*)(hp + ((c_) * 4 + 3) * BB);          \
        } while (0)

        LOADH(0); LOADH(1); LOADH(2);
        #pragma unroll
        for (int c = 0; c < 8; ++c) {
            if (c < 5) LOADH(c + 3);       // prefetch distance 3 iterations
            #pragma unroll
            for (int s = 0; s < 12; ++s) {
                float4 u = Up[(s * 8 + c) * 4];
                acc[s].x += u.x * hb[c][0].x + u.y * hb[c][1].x + u.z * hb[c][2].x + u.w * hb[c][3].x;
                acc[s].y += u.x * hb[c][0].y + u.y * hb[c][1].y + u.z * hb[c][2].y + u.w * hb[c][3].y;
                acc[s].z += u.x * hb[c][0].z + u.y * hb[c][1].z + u.z * hb[c][2].z + u.w * hb[c][3].z;
                acc[s].w += u.x * hb[c][0].w + u.y * hb[c][1].w + u.z * hb[c][2].w + u.w * hb[c][3].w;
            }
        }
        #undef LOADH

        // ---- write per-thread partials (batches contiguous: b128) ----
        #pragma unroll
        for (int s = 0; s < 12; ++s) red4[w][kk][s][bq] = acc[s];
        __syncthreads();

        // ---- gating (tid < 256): unit u0+w, batch lane ----
        if (tid < 256) {
            const int j = w;
            const int bqi = lane >> 2, bc = lane & 3;
            float rz = brz, rr = brr, rh = brh;
            #pragma unroll
            for (int q = 0; q < 8; ++q)
                #pragma unroll
                for (int kx = 0; kx < 4; ++kx) {
                    rz += ((const float*)&red4[q][kx][j * 3 + 0][bqi])[bc];
                    rr += ((const float*)&red4[q][kx][j * 3 + 1][bqi])[bc];
                    rh += ((const float*)&red4[q][kx][j * 3 + 2][bqi])[bc];
                }
            float z  = 1.f / (1.f + expf(-(xz + rz)));
            float r  = 1.f / (1.f + expf(-(xr + rr)));
            float hh = tanhf(xh + r * rh);
            float hnew = z * hold + (1.f - z) * hh;
            if (tok == 0) hnew = hold;     // mask_zero: carry state

            // write-through stores (LLC-visible, no dirty L2 lines)
            __hip_atomic_store(&hn[(u0 + j) * BB + lane], hnew,
                               __ATOMIC_RELAXED, __HIP_MEMORY_SCOPE_SYSTEM);
            // per-step output -> consumed xz slice of xpT (coalesced);
            // transposed to out[] by outT_kernel afterwards
            __hip_atomic_store(&xpT[((size_t)t * N3 + u0 + j) * BB + lane], hnew,
                               __ATOMIC_RELAXED, __HIP_MEMORY_SCOPE_SYSTEM);
            if (t == TT - 1)
                __hip_atomic_store(&state_out[(size_t)lane * NU + u0 + j], hnew,
                                   __ATOMIC_RELAXED, __HIP_MEMORY_SCOPE_SYSTEM);
            hold = hnew;
        }

        // ---- barrier: drain WT stores, arrive, tree-spin, acquire-inv ----
        __builtin_amdgcn_s_waitcnt(0);     // stores drained (prefetch not yet issued)
        __syncthreads();

        // prefetch t+1 gating inputs while the barrier resolves (immutable
        // until our own step-t+1 store; values live in regs across the inv)
        if (tid < 256 && t + 1 < TT) {
            size_t xb = ((size_t)(t + 1) * N3 + u0 + w) * BB + lane;
            xz = xpT[xb];
            xr = xpT[xb + (size_t)NU * BB];
            xh = xpT[xb + (size_t)2 * NU * BB];
            tok = xT[(t + 1) * BB + lane];
        }

        if (tid == 0) {
            const unsigned g = (unsigned)blockIdx.x >> 5;   // 8 groups x 32
            unsigned old = __hip_atomic_fetch_add(&cnt[g * 32], 1u,
                               __ATOMIC_RELAXED, __HIP_MEMORY_SCOPE_SYSTEM);
            if (old == 32u * (unsigned)t + 31u)             // group rep
                __hip_atomic_fetch_add(&cnt[256], 1u,
                               __ATOMIC_RELAXED, __HIP_MEMORY_SCOPE_SYSTEM);
            const unsigned tgt = 8u * ((unsigned)t + 1u);
            unsigned v;
            long guard = 0;
            do {
                v = __hip_atomic_load(&cnt[256],
                                      __ATOMIC_RELAXED, __HIP_MEMORY_SCOPE_SYSTEM);
                if (v < tgt) __builtin_amdgcn_s_sleep(1);
            } while (v < tgt && ++guard < (1L << 24));
            // invalidate L1+L2 so next step's plain h loads re-fetch from LLC
            __builtin_amdgcn_fence(__ATOMIC_ACQUIRE, "");
        }
        __syncthreads();

        float* tmp = (float*)hc; hc = hn; hn = tmp;
    }
}

// ---------------------------------------------------------------------------
// Kernel 3: transpose per-step outputs from xpT's xz slices [T][U][B]
// into out [B][T][U]. Kernel-boundary cache semantics make the persist
// kernel's write-through stores visible.
// ---------------------------------------------------------------------------
__global__ __launch_bounds__(256) void outT_kernel(
    const float* __restrict__ xpT, float* __restrict__ out)
{
    __shared__ float tile[64][65];
    const int t = blockIdx.x, u0 = blockIdx.y * 64;
    const int lane = threadIdx.x & 63, row = threadIdx.x >> 6;
    #pragma unroll
    for (int r = row; r < 64; r += 4)
        tile[r][lane] = xpT[((size_t)t * N3 + u0 + r) * BB + lane];
    __syncthreads();
    #pragma unroll
    for (int b = row; b < 64; b += 4)
        out[((size_t)b * TT + t) * NU + u0 + lane] = tile[lane][b];
}

// ---------------------------------------------------------------------------
extern "C" void kernel_launch(void* const* d_in, const int* in_sizes, int n_in,
                              void* d_out, int out_size, void* d_ws, size_t ws_size,
                              hipStream_t stream) {
    const int*   x      = (const int*)d_in[0];
    const float* hidden = (const float*)d_in[1];
    const float* emb    = (const float*)d_in[2];
    const float* W      = (const float*)d_in[3];
    const float* U      = (const float*)d_in[4];
    const float* bvec   = (const float*)d_in[5];

    float* out = (float*)d_out;

    float*    xpT   = (float*)d_ws;                       // 50,331,648 floats
    float*    upack = xpT + (size_t)16384 * N3;           //  3,145,728 floats
    float*    h0    = upack + (size_t)3 * NU * NU;        //     65,536 floats
    float*    h1    = h0 + (size_t)NU * BB;               //     65,536 floats
    int*      xT    = (int*)(h1 + (size_t)NU * BB);       //     16,384 ints
    unsigned* cnt   = (unsigned*)(xT + TT * BB);          //        512 uints

    upack_kernel<<<dim3(96, 32), dim3(256), 0, stream>>>(U, upack);
    tokT_kernel<<<dim3(TT), dim3(64), 0, stream>>>(x, xT);
    hinit_kernel<<<dim3(256), dim3(256), 0, stream>>>(hidden, h0, cnt);
    xprojT_kernel<<<dim3(3072), dim3(256), 0, stream>>>(x, emb, W, bvec, xpT);

    void* args[] = {(void*)&xT, (void*)&upack, (void*)&bvec, (void*)&xpT,
                    (void*)&out, (void*)&hidden, (void*)&h0, (void*)&h1,
                    (void*)&cnt};
    hipLaunchCooperativeKernel((const void*)gru_persist, dim3(256), dim3(512),
                               args, 0, stream);

    outT_kernel<<<dim3(TT, 16), dim3(256), 0, stream>>>(xpT, out);
}

// Round 4
// 2292.654 us; speedup vs baseline: 3.4602x; 1.6814x over previous
//
#include <hip/hip_runtime.h>
#include <hip/hip_cooperative_groups.h>

#define BB 64      // batch
#define TT 256     // time
#define EE 256     // embed dim
#define NU 1024    // hidden units
#define N3 3072    // 3*NU

typedef __attribute__((ext_vector_type(8))) short bf16x8;
typedef __attribute__((ext_vector_type(4))) float f32x4;

__device__ __forceinline__ unsigned short f2bf(float f) {
    unsigned u = __float_as_uint(f);
    return (unsigned short)((u + 0x7FFFu + ((u >> 16) & 1u)) >> 16);
}

// ---------------------------------------------------------------------------
// Kernel 0a: pack U[k][g*NU+u] -> Upack[u*3+g][k]  (fp32, unchanged)
// ---------------------------------------------------------------------------
__global__ __launch_bounds__(256) void upack_kernel(
    const float* __restrict__ U, float* __restrict__ up)
{
    __shared__ float t32[32][33];
    const int c0 = blockIdx.x * 32, k0 = blockIdx.y * 32;
    const int tx = threadIdx.x & 31, ty = threadIdx.x >> 5;
    #pragma unroll
    for (int i = 0; i < 4; ++i) {
        int k = ty + i * 8;
        t32[k][tx] = U[(size_t)(k0 + k) * N3 + c0 + tx];
    }
    __syncthreads();
    #pragma unroll
    for (int i = 0; i < 4; ++i) {
        int cl = ty + i * 8;
        int c = c0 + cl;
        int u = c & 1023, g = c >> 10;
        up[(size_t)(u * 3 + g) * NU + k0 + tx] = t32[tx][cl];
    }
}

// ---------------------------------------------------------------------------
// Kernel 0b: transpose tokens; 0c: init h_bf16 (frag layout) + zero counters
// h_bf layout: elem((k,b)) = ((k>>3)*64 + b)*8 + (k&7)  -> B-frag loads are
// four 256B-contiguous chunks per wave.
// ---------------------------------------------------------------------------
__global__ __launch_bounds__(64) void tokT_kernel(
    const int* __restrict__ x, int* __restrict__ xT)
{
    const int t = blockIdx.x, b = threadIdx.x;
    xT[t * BB + b] = x[b * TT + t];
}

__global__ __launch_bounds__(256) void hinit_kernel(
    const float* __restrict__ hidden, unsigned short* __restrict__ hb0,
    unsigned* __restrict__ cnt)
{
    const int u = blockIdx.x * 4 + (threadIdx.x >> 6);
    const int b = threadIdx.x & 63;
    hb0[((u >> 3) * 64 + b) * 8 + (u & 7)] = f2bf(hidden[(size_t)b * NU + u]);
    if (blockIdx.x == 0) {
        cnt[threadIdx.x] = 0u;           // group counters (8 x 32-uint pad)
        cnt[threadIdx.x + 256] = 0u;     // root counter at cnt[256]
    }
}

// ---------------------------------------------------------------------------
// Kernel 1: xprojT[t][c][b] = (emb[x[b,t]] @ W + b0)[c]   (unchanged)
// ---------------------------------------------------------------------------
__global__ __launch_bounds__(256) void xprojT_kernel(
    const int* __restrict__ x, const float* __restrict__ emb,
    const float* __restrict__ W, const float* __restrict__ bias,
    float* __restrict__ xpT)
{
    __shared__ float AsT[32][132];
    __shared__ float Ws[32][132];
    __shared__ int toks[128];

    const int tid = threadIdx.x;
    const int mt = blockIdx.x / 24, nt = blockIdx.x % 24;
    const int m0 = mt * 128, n0 = nt * 128;

    if (tid < 128) {
        int mg = m0 + tid;
        toks[tid] = x[(mg & 63) * TT + (mg >> 6)];
    }
    __syncthreads();

    const int tx = tid & 15, ty = tid >> 4;
    float acc[8][8] = {};

    for (int kb = 0; kb < 8; ++kb) {
        const int k0 = kb * 32;
        if (kb) __syncthreads();
        #pragma unroll
        for (int i = 0; i < 4; ++i) {
            int idx = tid + 256 * i;
            int m = idx >> 3, c4 = idx & 7;
            float4 av = *(const float4*)(emb + (size_t)toks[m] * EE + k0 + c4 * 4);
            AsT[c4 * 4 + 0][m] = av.x; AsT[c4 * 4 + 1][m] = av.y;
            AsT[c4 * 4 + 2][m] = av.z; AsT[c4 * 4 + 3][m] = av.w;
            int r = idx >> 5, w4 = idx & 31;
            *(float4*)&Ws[r][w4 * 4] =
                *(const float4*)(W + (size_t)(k0 + r) * N3 + n0 + w4 * 4);
        }
        __syncthreads();
        #pragma unroll 8
        for (int kk = 0; kk < 32; ++kk) {
            float a8[8], w8[8];
            *(float4*)a8       = *(const float4*)&AsT[kk][ty * 8];
            *(float4*)(a8 + 4) = *(const float4*)&AsT[kk][ty * 8 + 4];
            *(float4*)w8       = *(const float4*)&Ws[kk][tx * 8];
            *(float4*)(w8 + 4) = *(const float4*)&Ws[kk][tx * 8 + 4];
            #pragma unroll
            for (int i = 0; i < 8; ++i)
                #pragma unroll
                for (int j = 0; j < 8; ++j) acc[i][j] += a8[i] * w8[j];
        }
    }

    float b8[8];
    *(float4*)b8       = *(const float4*)(bias + n0 + tx * 8);
    *(float4*)(b8 + 4) = *(const float4*)(bias + n0 + tx * 8 + 4);
    const int t0 = mt * 2 + (ty >> 3);
    const int bb0 = (ty & 7) * 8;
    #pragma unroll
    for (int j = 0; j < 8; ++j) {
        const int c = n0 + tx * 8 + j;
        float4 lo, hi;
        lo.x = acc[0][j] + b8[j]; lo.y = acc[1][j] + b8[j];
        lo.z = acc[2][j] + b8[j]; lo.w = acc[3][j] + b8[j];
        hi.x = acc[4][j] + b8[j]; hi.y = acc[5][j] + b8[j];
        hi.z = acc[6][j] + b8[j]; hi.w = acc[7][j] + b8[j];
        size_t base = ((size_t)t0 * N3 + c) * BB + bb0;
        *(float4*)(xpT + base)     = lo;
        *(float4*)(xpT + base + 4) = hi;
    }
}

// ---------------------------------------------------------------------------
// Kernel 2: persistent GRU scan, 256 blocks x 512 threads (coop launch).
// Coherence protocol IDENTICAL to R3 (WT system stores, plain loads, tree
// barrier, acquire fence -> buffer_inv).
//
// GEMM via MFMA bf16 this round:
//   - per block: C tile 16 rows x 64 batches, rows = g*4+du (12 real, 4 pad)
//   - A (U bf16) lives in 16 VGPRs per thread, loaded once in the prologue
//   - B (h bf16) read direct from global h_bf in frag layout (coalesced)
//   - K split 8 ways across waves; per wave 4 ntiles x 4 ksteps = 16 MFMAs
//   - wave partials -> red[w][ (n*4+reg)*64 + lane ] (32 KB, plain writes)
//   - gating sums 8 wave-partials per gate; element-trace verified:
//     value(du,b,g) at red[w*1024 + ((b>>4)*4+du)*64 + g*16 + (b&15)]
//   - h stored bf16 via 512B LDS stage -> one coalesced 8B WT store/batch
// Layout-permutation note: A and B both pack k as (lane>>4)*8+j; any
// hardware k-permutation applied identically to both operands leaves the
// dot product invariant, so only row/col = lane&15 and the m89-verified
// C layout (col=lane&15, row=(lane>>4)*4+reg) are load-bearing.
// ---------------------------------------------------------------------------
__global__ __launch_bounds__(512) void gru_persist(
    const int* __restrict__ xT, const float* __restrict__ upack,
    const float* __restrict__ bias, float* xpT,
    float* __restrict__ out, const float* __restrict__ hidden,
    unsigned short* hb0, unsigned short* hb1, unsigned* cnt)
{
    __shared__ float red[8 * 1024];        // 32 KB wave partials
    __shared__ unsigned short hstage[256]; // [b][du] bf16 staging

    const int tid = threadIdx.x;
    const int u0 = blockIdx.x * 4;
    const int w = tid >> 6;                // wave: k-eighth; du for tid<256
    const int lane = tid & 63;

    // ---- prologue: A-fragments (U bf16) into registers, once ----
    bf16x8 af[4];
    {
        const int row = lane & 15;
        #pragma unroll
        for (int s = 0; s < 4; ++s) {
            if (row < 12) {
                const int R = (u0 + (row & 3)) * 3 + (row >> 2);
                const int k0 = w * 128 + s * 32 + (lane >> 4) * 8;
                const float* p = upack + (size_t)R * NU + k0;
                float4 v0 = *(const float4*)p;
                float4 v1 = *(const float4*)(p + 4);
                af[s] = (bf16x8){ (short)f2bf(v0.x), (short)f2bf(v0.y),
                                  (short)f2bf(v0.z), (short)f2bf(v0.w),
                                  (short)f2bf(v1.x), (short)f2bf(v1.y),
                                  (short)f2bf(v1.z), (short)f2bf(v1.w) };
            } else {
                af[s] = (bf16x8){0, 0, 0, 0, 0, 0, 0, 0};
            }
        }
    }

    float hold = 0.f, brz = 0.f, brr = 0.f, brh = 0.f;
    float xz = 0.f, xr = 0.f, xh = 0.f; int tok = 1;
    if (tid < 256) {
        hold = hidden[(size_t)lane * NU + u0 + w];
        brz = bias[N3 + 0 * NU + u0 + w];
        brr = bias[N3 + 1 * NU + u0 + w];
        brh = bias[N3 + 2 * NU + u0 + w];
        size_t xb = ((size_t)0 * N3 + u0 + w) * BB + lane;
        xz = xpT[xb];
        xr = xpT[xb + (size_t)NU * BB];
        xh = xpT[xb + (size_t)2 * NU * BB];
        tok = xT[0 * BB + lane];
    }
    float* state_out = out + (size_t)BB * TT * NU;
    __syncthreads();

    const unsigned short* hc = hb0;
    unsigned short* hn = hb1;

    for (int t = 0; t < TT; ++t) {
        // ---- B-fragments from global h_bf (post-inv: LLC/L2) ----
        bf16x8 bv[4][4];
        #pragma unroll
        for (int n = 0; n < 4; ++n)
            #pragma unroll
            for (int s = 0; s < 4; ++s) {
                const int ew = w * 16 + s * 4 + (lane >> 4);
                bv[n][s] = *(const bf16x8*)(hc +
                    (size_t)(ew * 64 + n * 16 + (lane & 15)) * 8);
            }

        // ---- MFMA: C[n] accumulates over the wave's 4 k-steps ----
        f32x4 c0 = {0.f, 0.f, 0.f, 0.f}, c1 = c0, c2 = c0, c3 = c0;
        #pragma unroll
        for (int s = 0; s < 4; ++s) {
            c0 = __builtin_amdgcn_mfma_f32_16x16x32_bf16(af[s], bv[0][s], c0, 0, 0, 0);
            c1 = __builtin_amdgcn_mfma_f32_16x16x32_bf16(af[s], bv[1][s], c1, 0, 0, 0);
            c2 = __builtin_amdgcn_mfma_f32_16x16x32_bf16(af[s], bv[2][s], c2, 0, 0, 0);
            c3 = __builtin_amdgcn_mfma_f32_16x16x32_bf16(af[s], bv[3][s], c3, 0, 0, 0);
        }
        #pragma unroll
        for (int r = 0; r < 4; ++r) {
            red[w * 1024 + (0 * 4 + r) * 64 + lane] = c0[r];
            red[w * 1024 + (1 * 4 + r) * 64 + lane] = c1[r];
            red[w * 1024 + (2 * 4 + r) * 64 + lane] = c2[r];
            red[w * 1024 + (3 * 4 + r) * 64 + lane] = c3[r];
        }
        __syncthreads();

        // ---- gating (tid < 256): unit u0+w, batch lane ----
        if (tid < 256) {
            const int du = w, b = lane;
            float rz = brz, rr = brr, rh = brh;
            const int base = ((b >> 4) * 4 + du) * 64 + (b & 15);
            #pragma unroll
            for (int q = 0; q < 8; ++q) {
                rz += red[q * 1024 + base];        // g=0
                rr += red[q * 1024 + base + 16];   // g=1
                rh += red[q * 1024 + base + 32];   // g=2
            }
            float z  = 1.f / (1.f + expf(-(xz + rz)));
            float r  = 1.f / (1.f + expf(-(xr + rr)));
            float hh = tanhf(xh + r * rh);
            float hnew = z * hold + (1.f - z) * hh;
            if (tok == 0) hnew = hold;     // mask_zero: carry state

            // per-step output -> consumed xz slice of xpT (coalesced WT)
            __hip_atomic_store(&xpT[((size_t)t * N3 + u0 + du) * BB + b], hnew,
                               __ATOMIC_RELAXED, __HIP_MEMORY_SCOPE_SYSTEM);
            if (t == TT - 1)
                __hip_atomic_store(&state_out[(size_t)b * NU + u0 + du], hnew,
                                   __ATOMIC_RELAXED, __HIP_MEMORY_SCOPE_SYSTEM);
            hstage[b * 4 + du] = f2bf(hnew);
            hold = hnew;
        }
        __syncthreads();

        // ---- h_bf store: wave 4 packs 4 units x 64 batches, 8B/lane WT ----
        if (w == 4) {
            uint2 hv = *(const uint2*)&hstage[lane * 4];
            unsigned long long hv64 =
                ((unsigned long long)hv.y << 32) | (unsigned long long)hv.x;
            __hip_atomic_store(
                (unsigned long long*)(hn + (size_t)(u0 >> 3) * 512 + (u0 & 7) + lane * 8),
                hv64, __ATOMIC_RELAXED, __HIP_MEMORY_SCOPE_SYSTEM);
        }

        // ---- barrier: drain WT stores, arrive, tree-spin, acquire-inv ----
        __builtin_amdgcn_s_waitcnt(0);     // each wave drains its own stores
        __syncthreads();

        // prefetch t+1 gating inputs while the barrier resolves
        if (tid < 256 && t + 1 < TT) {
            size_t xb = ((size_t)(t + 1) * N3 + u0 + w) * BB + lane;
            xz = xpT[xb];
            xr = xpT[xb + (size_t)NU * BB];
            xh = xpT[xb + (size_t)2 * NU * BB];
            tok = xT[(t + 1) * BB + lane];
        }

        if (tid == 0) {
            const unsigned g = (unsigned)blockIdx.x >> 5;   // 8 groups x 32
            unsigned old = __hip_atomic_fetch_add(&cnt[g * 32], 1u,
                               __ATOMIC_RELAXED, __HIP_MEMORY_SCOPE_SYSTEM);
            if (old == 32u * (unsigned)t + 31u)             // group rep
                __hip_atomic_fetch_add(&cnt[256], 1u,
                               __ATOMIC_RELAXED, __HIP_MEMORY_SCOPE_SYSTEM);
            const unsigned tgt = 8u * ((unsigned)t + 1u);
            unsigned v;
            long guard = 0;
            do {
                v = __hip_atomic_load(&cnt[256],
                                      __ATOMIC_RELAXED, __HIP_MEMORY_SCOPE_SYSTEM);
                if (v < tgt) __builtin_amdgcn_s_sleep(1);
            } while (v < tgt && ++guard < (1L << 24));
            // invalidate L1+L2 so next step's plain loads re-fetch from LLC
            __builtin_amdgcn_fence(__ATOMIC_ACQUIRE, "");
        }
        __syncthreads();

        const unsigned short* tmp = hc; hc = hn; hn = (unsigned short*)tmp;
    }
}

// ---------------------------------------------------------------------------
// Kernel 3: transpose per-step outputs from xpT's xz slices [T][U][B]
// into out [B][T][U].  (unchanged)
// ---------------------------------------------------------------------------
__global__ __launch_bounds__(256) void outT_kernel(
    const float* __restrict__ xpT, float* __restrict__ out)
{
    __shared__ float tile[64][65];
    const int t = blockIdx.x, u0 = blockIdx.y * 64;
    const int lane = threadIdx.x & 63, row = threadIdx.x >> 6;
    #pragma unroll
    for (int r = row; r < 64; r += 4)
        tile[r][lane] = xpT[((size_t)t * N3 + u0 + r) * BB + lane];
    __syncthreads();
    #pragma unroll
    for (int b = row; b < 64; b += 4)
        out[((size_t)b * TT + t) * NU + u0 + lane] = tile[lane][b];
}

// ---------------------------------------------------------------------------
extern "C" void kernel_launch(void* const* d_in, const int* in_sizes, int n_in,
                              void* d_out, int out_size, void* d_ws, size_t ws_size,
                              hipStream_t stream) {
    const int*   x      = (const int*)d_in[0];
    const float* hidden = (const float*)d_in[1];
    const float* emb    = (const float*)d_in[2];
    const float* W      = (const float*)d_in[3];
    const float* U      = (const float*)d_in[4];
    const float* bvec   = (const float*)d_in[5];

    float* out = (float*)d_out;

    float*          xpT   = (float*)d_ws;                     // 50,331,648 f
    float*          upck  = xpT + (size_t)16384 * N3;         //  3,145,728 f
    unsigned short* hb0   = (unsigned short*)(upck + (size_t)3 * NU * NU);
    unsigned short* hb1   = hb0 + (size_t)NU * BB;            // 65,536 u16 ea
    int*            xT    = (int*)(hb1 + (size_t)NU * BB);    // 16,384 ints
    unsigned*       cnt   = (unsigned*)(xT + TT * BB);        // 512 uints

    upack_kernel<<<dim3(96, 32), dim3(256), 0, stream>>>(U, upck);
    tokT_kernel<<<dim3(TT), dim3(64), 0, stream>>>(x, xT);
    hinit_kernel<<<dim3(256), dim3(256), 0, stream>>>(hidden, hb0, cnt);
    xprojT_kernel<<<dim3(3072), dim3(256), 0, stream>>>(x, emb, W, bvec, xpT);

    void* args[] = {(void*)&xT, (void*)&upck, (void*)&bvec, (void*)&xpT,
                    (void*)&out, (void*)&hidden, (void*)&hb0, (void*)&hb1,
                    (void*)&cnt};
    hipLaunchCooperativeKernel((const void*)gru_persist, dim3(256), dim3(512),
                               args, 0, stream);

    outT_kernel<<<dim3(TT, 16), dim3(256), 0, stream>>>(xpT, out);
}

// Round 5
// 2050.524 us; speedup vs baseline: 3.8688x; 1.1181x over previous
//
#include <hip/hip_runtime.h>
#include <hip/hip_cooperative_groups.h>

#define BB 64      // batch
#define TT 256     // time
#define EE 256     // embed dim
#define NU 1024    // hidden units
#define N3 3072    // 3*NU

typedef __attribute__((ext_vector_type(8))) short bf16x8;
typedef __attribute__((ext_vector_type(4))) float f32x4;

__device__ __forceinline__ unsigned short f2bf(float f) {
    unsigned u = __float_as_uint(f);
    return (unsigned short)((u + 0x7FFFu + ((u >> 16) & 1u)) >> 16);
}

// ---------------------------------------------------------------------------
// Kernel 0a: pack U[k][g*NU+u] -> Upack[u*3+g][k]  (fp32, unchanged)
// ---------------------------------------------------------------------------
__global__ __launch_bounds__(256) void upack_kernel(
    const float* __restrict__ U, float* __restrict__ up)
{
    __shared__ float t32[32][33];
    const int c0 = blockIdx.x * 32, k0 = blockIdx.y * 32;
    const int tx = threadIdx.x & 31, ty = threadIdx.x >> 5;
    #pragma unroll
    for (int i = 0; i < 4; ++i) {
        int k = ty + i * 8;
        t32[k][tx] = U[(size_t)(k0 + k) * N3 + c0 + tx];
    }
    __syncthreads();
    #pragma unroll
    for (int i = 0; i < 4; ++i) {
        int cl = ty + i * 8;
        int c = c0 + cl;
        int u = c & 1023, g = c >> 10;
        up[(size_t)(u * 3 + g) * NU + k0 + tx] = t32[tx][cl];
    }
}

// ---------------------------------------------------------------------------
// Kernel 0b: transpose tokens; 0c: init h_bf16 (frag layout) + zero counters
// h_bf layout: elem((k,b)) = ((k>>3)*64 + b)*8 + (k&7)
// ---------------------------------------------------------------------------
__global__ __launch_bounds__(64) void tokT_kernel(
    const int* __restrict__ x, int* __restrict__ xT)
{
    const int t = blockIdx.x, b = threadIdx.x;
    xT[t * BB + b] = x[b * TT + t];
}

__global__ __launch_bounds__(256) void hinit_kernel(
    const float* __restrict__ hidden, unsigned short* __restrict__ hb0,
    unsigned* __restrict__ cnt)
{
    const int u = blockIdx.x * 4 + (threadIdx.x >> 6);
    const int b = threadIdx.x & 63;
    hb0[((u >> 3) * 64 + b) * 8 + (u & 7)] = f2bf(hidden[(size_t)b * NU + u]);
    if (blockIdx.x == 0) {
        cnt[threadIdx.x] = 0u;           // 8 group counters, 128B apart
        cnt[threadIdx.x + 256] = 0u;
    }
}

// ---------------------------------------------------------------------------
// Kernel 1: xprojT[t][c][b] = (emb[x[b,t]] @ W + b0)[c]   (unchanged)
// ---------------------------------------------------------------------------
__global__ __launch_bounds__(256) void xprojT_kernel(
    const int* __restrict__ x, const float* __restrict__ emb,
    const float* __restrict__ W, const float* __restrict__ bias,
    float* __restrict__ xpT)
{
    __shared__ float AsT[32][132];
    __shared__ float Ws[32][132];
    __shared__ int toks[128];

    const int tid = threadIdx.x;
    const int mt = blockIdx.x / 24, nt = blockIdx.x % 24;
    const int m0 = mt * 128, n0 = nt * 128;

    if (tid < 128) {
        int mg = m0 + tid;
        toks[tid] = x[(mg & 63) * TT + (mg >> 6)];
    }
    __syncthreads();

    const int tx = tid & 15, ty = tid >> 4;
    float acc[8][8] = {};

    for (int kb = 0; kb < 8; ++kb) {
        const int k0 = kb * 32;
        if (kb) __syncthreads();
        #pragma unroll
        for (int i = 0; i < 4; ++i) {
            int idx = tid + 256 * i;
            int m = idx >> 3, c4 = idx & 7;
            float4 av = *(const float4*)(emb + (size_t)toks[m] * EE + k0 + c4 * 4);
            AsT[c4 * 4 + 0][m] = av.x; AsT[c4 * 4 + 1][m] = av.y;
            AsT[c4 * 4 + 2][m] = av.z; AsT[c4 * 4 + 3][m] = av.w;
            int r = idx >> 5, w4 = idx & 31;
            *(float4*)&Ws[r][w4 * 4] =
                *(const float4*)(W + (size_t)(k0 + r) * N3 + n0 + w4 * 4);
        }
        __syncthreads();
        #pragma unroll 8
        for (int kk = 0; kk < 32; ++kk) {
            float a8[8], w8[8];
            *(float4*)a8       = *(const float4*)&AsT[kk][ty * 8];
            *(float4*)(a8 + 4) = *(const float4*)&AsT[kk][ty * 8 + 4];
            *(float4*)w8       = *(const float4*)&Ws[kk][tx * 8];
            *(float4*)(w8 + 4) = *(const float4*)&Ws[kk][tx * 8 + 4];
            #pragma unroll
            for (int i = 0; i < 8; ++i)
                #pragma unroll
                for (int j = 0; j < 8; ++j) acc[i][j] += a8[i] * w8[j];
        }
    }

    float b8[8];
    *(float4*)b8       = *(const float4*)(bias + n0 + tx * 8);
    *(float4*)(b8 + 4) = *(const float4*)(bias + n0 + tx * 8 + 4);
    const int t0 = mt * 2 + (ty >> 3);
    const int bb0 = (ty & 7) * 8;
    #pragma unroll
    for (int j = 0; j < 8; ++j) {
        const int c = n0 + tx * 8 + j;
        float4 lo, hi;
        lo.x = acc[0][j] + b8[j]; lo.y = acc[1][j] + b8[j];
        lo.z = acc[2][j] + b8[j]; lo.w = acc[3][j] + b8[j];
        hi.x = acc[4][j] + b8[j]; hi.y = acc[5][j] + b8[j];
        hi.z = acc[6][j] + b8[j]; hi.w = acc[7][j] + b8[j];
        size_t base = ((size_t)t0 * N3 + c) * BB + bb0;
        *(float4*)(xpT + base)     = lo;
        *(float4*)(xpT + base + 4) = hi;
    }
}

// ---------------------------------------------------------------------------
// Kernel 2: persistent GRU scan, 64 blocks x 512 threads (coop launch).
// Coherence protocol IDENTICAL to R4 (WT system stores, plain loads,
// counter barrier, acquire fence -> buffer_inv).
//
// This round: 64 blocks x 16 units (was 256 x 4):
//   - C tile = 48 rows (3 gate row-tiles x 16 unit rows, ZERO padding) x 64 b
//   - A (U bf16): 12 frags in regs; B (h bf16) loaded once/step, reused 3x
//     -> total h read traffic 4x down (1MB/XCD/step, L2 refilled once)
//   - barrier: 64 arrivals, 8 groups x 8, NO root hop: tid0 polls the 8
//     group lines directly (8 parallel loads = one LLC round trip)
//   - red2[w][g][n][lane] f32x4 (96KB) written as b128; gating threads
//     (du=tid>>5, batches b,b+32) sum 8 wave-partials per gate
//   - h store: hstage[64][20] bf16 -> waves 4,5 emit coalesced 2x8B WT
// C-layout chain (R4-silicon-verified convention): row=(lane>>4)*4+reg,
// col=lane&15; rowtile = gate, row = unit offset du.
// ---------------------------------------------------------------------------
__global__ __launch_bounds__(512) void gru_persist(
    const int* __restrict__ xT, const float* __restrict__ upack,
    const float* __restrict__ bias, float* xpT,
    float* __restrict__ out, const float* __restrict__ hidden,
    unsigned short* hb0, unsigned short* hb1, unsigned* cnt)
{
    __shared__ f32x4 red2[6144];            // 96 KB: [w][g][n][lane], reg inner
    __shared__ unsigned short hstage[64 * 20]; // 2.5 KB: [b][du(16)+pad]

    const int tid = threadIdx.x;
    const int U0 = blockIdx.x * 16;
    const int w = tid >> 6;                 // wave: k-eighth
    const int lane = tid & 63;

    // gating identity: unit U0+gdu, batches gbA and gbA+32
    const int gdu = tid >> 5;               // 0..15
    const int gbA = tid & 31;               // 0..31

    // ---- prologue: A-fragments (U bf16) into registers, once ----
    bf16x8 af[3][4];
    {
        const int du = lane & 15;
        #pragma unroll
        for (int g = 0; g < 3; ++g)
            #pragma unroll
            for (int s = 0; s < 4; ++s) {
                const int k0 = w * 128 + s * 32 + (lane >> 4) * 8;
                const float* p = upack + (size_t)((U0 + du) * 3 + g) * NU + k0;
                float4 v0 = *(const float4*)p;
                float4 v1 = *(const float4*)(p + 4);
                af[g][s] = (bf16x8){ (short)f2bf(v0.x), (short)f2bf(v0.y),
                                     (short)f2bf(v0.z), (short)f2bf(v0.w),
                                     (short)f2bf(v1.x), (short)f2bf(v1.y),
                                     (short)f2bf(v1.z), (short)f2bf(v1.w) };
            }
    }

    float holdA = hidden[(size_t)gbA * NU + U0 + gdu];
    float holdB = hidden[(size_t)(gbA + 32) * NU + U0 + gdu];
    const float brz = bias[N3 + 0 * NU + U0 + gdu];
    const float brr = bias[N3 + 1 * NU + U0 + gdu];
    const float brh = bias[N3 + 2 * NU + U0 + gdu];
    float xzA, xrA, xhA, xzB, xrB, xhB; int tokA, tokB;
    {
        size_t xb = ((size_t)0 * N3 + U0 + gdu) * BB + gbA;
        xzA = xpT[xb];                      xzB = xpT[xb + 32];
        xrA = xpT[xb + (size_t)NU * BB];    xrB = xpT[xb + (size_t)NU * BB + 32];
        xhA = xpT[xb + (size_t)2 * NU * BB];xhB = xpT[xb + (size_t)2 * NU * BB + 32];
        tokA = xT[0 * BB + gbA];            tokB = xT[0 * BB + gbA + 32];
    }
    float* state_out = out + (size_t)BB * TT * NU;
    __syncthreads();

    const unsigned short* hc = hb0;
    unsigned short* hn = hb1;

    for (int t = 0; t < TT; ++t) {
        // ---- B-fragments from global h_bf (post-inv: refilled once/XCD) ----
        bf16x8 bv[4][4];
        #pragma unroll
        for (int n = 0; n < 4; ++n)
            #pragma unroll
            for (int s = 0; s < 4; ++s) {
                const int ew = w * 16 + s * 4 + (lane >> 4);
                bv[n][s] = *(const bf16x8*)(hc +
                    (size_t)(ew * 64 + n * 16 + (lane & 15)) * 8);
            }

        // ---- MFMA: 3 gate-tiles x 4 batch-tiles, K=128 per wave ----
        f32x4 c[3][4];
        #pragma unroll
        for (int g = 0; g < 3; ++g)
            #pragma unroll
            for (int n = 0; n < 4; ++n) c[g][n] = (f32x4){0.f, 0.f, 0.f, 0.f};
        #pragma unroll
        for (int s = 0; s < 4; ++s)
            #pragma unroll
            for (int g = 0; g < 3; ++g)
                #pragma unroll
                for (int n = 0; n < 4; ++n)
                    c[g][n] = __builtin_amdgcn_mfma_f32_16x16x32_bf16(
                        af[g][s], bv[n][s], c[g][n], 0, 0, 0);

        #pragma unroll
        for (int g = 0; g < 3; ++g)
            #pragma unroll
            for (int n = 0; n < 4; ++n)
                red2[((w * 3 + g) * 4 + n) * 64 + lane] = c[g][n];
        __syncthreads();

        // ---- gating: unit U0+gdu, batches gbA and gbA+32 ----
        {
            const int lA = (gdu >> 2) * 16 + (gbA & 15);
            const int rsub = gdu & 3;
            const int nA = gbA >> 4;        // 0 or 1; batch+32 -> nA+2
            float rzA = brz, rrA = brr, rhA = brh;
            float rzB = brz, rrB = brr, rhB = brh;
            #pragma unroll
            for (int q = 0; q < 8; ++q) {
                const int qb = (q * 3) * 4;
                float vA, vB;
                vA = ((const float*)&red2[(qb + 0 * 4 + nA) * 64 + lA])[rsub];
                vB = ((const float*)&red2[(qb + 0 * 4 + nA + 2) * 64 + lA])[rsub];
                rzA += vA; rzB += vB;
                vA = ((const float*)&red2[(qb + 1 * 4 + nA) * 64 + lA])[rsub];
                vB = ((const float*)&red2[(qb + 1 * 4 + nA + 2) * 64 + lA])[rsub];
                rrA += vA; rrB += vB;
                vA = ((const float*)&red2[(qb + 2 * 4 + nA) * 64 + lA])[rsub];
                vB = ((const float*)&red2[(qb + 2 * 4 + nA + 2) * 64 + lA])[rsub];
                rhA += vA; rhB += vB;
            }
            float zA  = 1.f / (1.f + expf(-(xzA + rzA)));
            float rA  = 1.f / (1.f + expf(-(xrA + rrA)));
            float hhA = tanhf(xhA + rA * rhA);
            float hnewA = zA * holdA + (1.f - zA) * hhA;
            if (tokA == 0) hnewA = holdA;
            float zB  = 1.f / (1.f + expf(-(xzB + rzB)));
            float rB  = 1.f / (1.f + expf(-(xrB + rrB)));
            float hhB = tanhf(xhB + rB * rhB);
            float hnewB = zB * holdB + (1.f - zB) * hhB;
            if (tokB == 0) hnewB = holdB;

            // per-step output -> consumed xz slice of xpT (coalesced WT)
            size_t ob = ((size_t)t * N3 + U0 + gdu) * BB + gbA;
            __hip_atomic_store(&xpT[ob], hnewA,
                               __ATOMIC_RELAXED, __HIP_MEMORY_SCOPE_SYSTEM);
            __hip_atomic_store(&xpT[ob + 32], hnewB,
                               __ATOMIC_RELAXED, __HIP_MEMORY_SCOPE_SYSTEM);
            if (t == TT - 1) {
                __hip_atomic_store(&state_out[(size_t)gbA * NU + U0 + gdu], hnewA,
                                   __ATOMIC_RELAXED, __HIP_MEMORY_SCOPE_SYSTEM);
                __hip_atomic_store(&state_out[(size_t)(gbA + 32) * NU + U0 + gdu], hnewB,
                                   __ATOMIC_RELAXED, __HIP_MEMORY_SCOPE_SYSTEM);
            }
            hstage[gbA * 20 + gdu] = f2bf(hnewA);
            hstage[(gbA + 32) * 20 + gdu] = f2bf(hnewB);
            holdA = hnewA; holdB = hnewB;
        }
        __syncthreads();

        // ---- h_bf store: waves 4,5 pack 8 units x 64 batches each ----
        if (w == 4 || w == 5) {
            const int g2 = w - 4;
            unsigned long long lo =
                *(const unsigned long long*)&hstage[lane * 20 + 8 * g2];
            unsigned long long hi =
                *(const unsigned long long*)&hstage[lane * 20 + 8 * g2 + 4];
            unsigned short* dst = hn + ((size_t)((U0 >> 3) + g2) * 64 + lane) * 8;
            __hip_atomic_store((unsigned long long*)dst, lo,
                               __ATOMIC_RELAXED, __HIP_MEMORY_SCOPE_SYSTEM);
            __hip_atomic_store((unsigned long long*)(dst + 4), hi,
                               __ATOMIC_RELAXED, __HIP_MEMORY_SCOPE_SYSTEM);
        }

        // ---- barrier: drain WT stores, arrive, flat 8-line poll, inv ----
        __builtin_amdgcn_s_waitcnt(0);
        __syncthreads();

        // prefetch t+1 gating inputs while the barrier resolves
        if (t + 1 < TT) {
            size_t xb = ((size_t)(t + 1) * N3 + U0 + gdu) * BB + gbA;
            xzA = xpT[xb];                      xzB = xpT[xb + 32];
            xrA = xpT[xb + (size_t)NU * BB];    xrB = xpT[xb + (size_t)NU * BB + 32];
            xhA = xpT[xb + (size_t)2 * NU * BB];xhB = xpT[xb + (size_t)2 * NU * BB + 32];
            tokA = xT[(t + 1) * BB + gbA];      tokB = xT[(t + 1) * BB + gbA + 32];
        }

        if (tid == 0) {
            const unsigned g = (unsigned)blockIdx.x >> 3;   // 8 groups x 8
            __hip_atomic_fetch_add(&cnt[g * 32], 1u,
                                   __ATOMIC_RELAXED, __HIP_MEMORY_SCOPE_SYSTEM);
            const unsigned tgt = 8u * ((unsigned)t + 1u);
            unsigned mn;
            long guard = 0;
            do {
                mn = 0xffffffffu;
                #pragma unroll
                for (int g8 = 0; g8 < 8; ++g8) {
                    unsigned v = __hip_atomic_load(&cnt[g8 * 32],
                                  __ATOMIC_RELAXED, __HIP_MEMORY_SCOPE_SYSTEM);
                    mn = v < mn ? v : mn;
                }
                if (mn < tgt) __builtin_amdgcn_s_sleep(1);
            } while (mn < tgt && ++guard < (1L << 24));
            // invalidate L1+L2 so next step's plain h loads re-fetch fresh
            __builtin_amdgcn_fence(__ATOMIC_ACQUIRE, "");
        }
        __syncthreads();

        const unsigned short* tmp = hc; hc = hn; hn = (unsigned short*)tmp;
    }
}

// ---------------------------------------------------------------------------
// Kernel 3: transpose per-step outputs from xpT's xz slices [T][U][B]
// into out [B][T][U].  (unchanged)
// ---------------------------------------------------------------------------
__global__ __launch_bounds__(256) void outT_kernel(
    const float* __restrict__ xpT, float* __restrict__ out)
{
    __shared__ float tile[64][65];
    const int t = blockIdx.x, u0 = blockIdx.y * 64;
    const int lane = threadIdx.x & 63, row = threadIdx.x >> 6;
    #pragma unroll
    for (int r = row; r < 64; r += 4)
        tile[r][lane] = xpT[((size_t)t * N3 + u0 + r) * BB + lane];
    __syncthreads();
    #pragma unroll
    for (int b = row; b < 64; b += 4)
        out[((size_t)b * TT + t) * NU + u0 + lane] = tile[lane][b];
}

// ---------------------------------------------------------------------------
extern "C" void kernel_launch(void* const* d_in, const int* in_sizes, int n_in,
                              void* d_out, int out_size, void* d_ws, size_t ws_size,
                              hipStream_t stream) {
    const int*   x      = (const int*)d_in[0];
    const float* hidden = (const float*)d_in[1];
    const float* emb    = (const float*)d_in[2];
    const float* W      = (const float*)d_in[3];
    const float* U      = (const float*)d_in[4];
    const float* bvec   = (const float*)d_in[5];

    float* out = (float*)d_out;

    float*          xpT   = (float*)d_ws;                     // 50,331,648 f
    float*          upck  = xpT + (size_t)16384 * N3;         //  3,145,728 f
    unsigned short* hb0   = (unsigned short*)(upck + (size_t)3 * NU * NU);
    unsigned short* hb1   = hb0 + (size_t)NU * BB;            // 65,536 u16 ea
    int*            xT    = (int*)(hb1 + (size_t)NU * BB);    // 16,384 ints
    unsigned*       cnt   = (unsigned*)(xT + TT * BB);        // 512 uints

    upack_kernel<<<dim3(96, 32), dim3(256), 0, stream>>>(U, upck);
    tokT_kernel<<<dim3(TT), dim3(64), 0, stream>>>(x, xT);
    hinit_kernel<<<dim3(256), dim3(256), 0, stream>>>(hidden, hb0, cnt);
    xprojT_kernel<<<dim3(3072), dim3(256), 0, stream>>>(x, emb, W, bvec, xpT);

    void* args[] = {(void*)&xT, (void*)&upck, (void*)&bvec, (void*)&xpT,
                    (void*)&out, (void*)&hidden, (void*)&hb0, (void*)&hb1,
                    (void*)&cnt};
    hipLaunchCooperativeKernel((const void*)gru_persist, dim3(64), dim3(512),
                               args, 0, stream);

    outT_kernel<<<dim3(TT, 16), dim3(256), 0, stream>>>(xpT, out);
}